// Round 6
// baseline (35144.336 us; speedup 1.0000x reference)
//
#include <hip/hip_runtime.h>

#define NT 1024

__device__ __forceinline__ float fast_sigmoid(float x) { return 1.f/(1.f + __expf(-x)); }
__device__ __forceinline__ float fast_tanh(float x) {
  float t = __expf(-2.f*fabsf(x));
  float y = (1.f - t)/(1.f + t);
  return copysignf(y, x);
}
__device__ __forceinline__ void acc4(float& a, float4 u, float4 v) {
  a = fmaf(u.x, v.x, a); a = fmaf(u.y, v.y, a); a = fmaf(u.z, v.z, a); a = fmaf(u.w, v.w, a);
}
#define FMA4(A_, S_, V_) do { (A_).x = fmaf((S_),(V_).x,(A_).x); (A_).y = fmaf((S_),(V_).y,(A_).y); \
                              (A_).z = fmaf((S_),(V_).z,(A_).z); (A_).w = fmaf((S_),(V_).w,(A_).w); } while(0)

// ~155 KB LDS. Same layout as round 5 (proven structure).
struct alignas(16) SmemScan {
  float h[56][132];     // step-input h; col 128 == 1.0 (bias folding); pads 0
  float hh[56][132];    // hhat = GRU output; col 128 == 1.0; pads 0
  float v[56][132];
  union {
    float z[53][132];   // phase-2 output, read in phase 3, dead after B4
    float G[2][56][60]; // GA=G[0], GB=G[1]: squaring ping-pong (born at k=0)
  } ab;
  float S[56][60];
  float G0[56][60];
  float u384[384], v00[384];
  float gb[2812];       // gate_b cached (constant)
  float xt[56];
  float pv[56], y1[56], y2[56];
  int   gmax[9];
  float sc_ev;
};

// ---------------- prep kernels (run once per launch) ----------------
// Lane-major repack of the GRU hidden weights:
//   Wp1[((g*33 + q)*128 + f)*4 + j] = Whh_hat[4q+j][g*128+f]
__global__ void prep_wp1(const float* __restrict__ w_hh, const float* __restrict__ b_hh,
                         float* __restrict__ Wp1) {
  int idx = blockIdx.x*256 + threadIdx.x;
  if (idx >= 3*33*128*4) return;            // 50688
  int j = idx & 3;
  int f = (idx >> 2) & 127;
  int qg = idx >> 9;
  int q = qg % 33;
  int g = qg / 33;
  int k = 4*q + j;
  int col = g*128 + f;
  float v = 0.f;
  if (k < 128) v = w_hh[k*384 + col];
  else if (k == 128) v = b_hh[col];
  Wp1[idx] = v;
}

// Lane-major repack of the fused attention weights.
__global__ void prep_wp2(const float* __restrict__ q_w, const float* __restrict__ q_b,
                         const float* __restrict__ k_w, const float* __restrict__ k_b,
                         const float* __restrict__ v_w, const float* __restrict__ v_b,
                         float* __restrict__ Wp2) {
  int idx = blockIdx.x*256 + threadIdx.x;
  if (idx >= 33924) return;                 // 2*33*128*4 + 132
  float val = 0.f;
  if (idx < 33792) {
    int j = idx & 3;
    int f = (idx >> 2) & 127;
    int qp = idx >> 9;
    int q = qp % 33;
    int p = qp / 33;
    int u = 2*f + p;                        // 0..255
    int k = 4*q + j;                        // 0..131
    if (u < 129) {
      if (k <= 128) {
        const float* qa = (k < 128) ? (q_w + k*128) : q_b;
        const float* kb = (u < 128) ? (k_w + u*128) : k_b;
        float s = 0.f;
        for (int d = 0; d < 128; ++d) s = fmaf(qa[d], kb[d], s);
        val = s;
      }
    } else {
      int f2 = u - 129;
      if (k < 128) val = v_w[k*128 + f2];
      else if (k == 128) val = v_b[f2];
    }
  } else {
    int c = idx - 33792;                    // W256[c]
    if (c < 128) val = v_w[c*128 + 127];
    else if (c == 128) val = v_b[127];
  }
  Wp2[idx] = val;
}

// ---------------- main scan kernel: one block per batch ----------------
// amdgpu_waves_per_eu(4,4): LDS forces 1 block/CU = exactly 4 waves/EU, so let
// the register allocator use the full 128-VGPR budget (prevents round-3 spills).
__global__ void __launch_bounds__(1024)
__attribute__((amdgpu_waves_per_eu(4, 4)))
scan_kernel(const float* __restrict__ x, const float* __restrict__ emb_w,
            const float* __restrict__ emb_b, const float* __restrict__ w_ih,
            const float* __restrict__ b_ih, const float* __restrict__ Wp1,
            const float* __restrict__ Wp2, const float* __restrict__ gate_b,
            float* __restrict__ out_align)
{
  extern __shared__ char smem_raw[];
  SmemScan& sm = *reinterpret_cast<SmemScan*>(smem_raw);
  const int b = blockIdx.x;
  const int tid = threadIdx.x;
  const int wv = tid >> 6;
  const int lane = tid & 63;

  // ---- setup: u384 = emb_w@w_ih, v00 = emb_b@w_ih + b_ih ----
  for (int j = tid; j < 384; j += NT) {
    float su = 0.f, sv = 0.f;
    for (int m = 0; m < 64; ++m) {
      float w = w_ih[m*384 + j];
      su = fmaf(emb_w[m], w, su);
      sv = fmaf(emb_b[m], w, sv);
    }
    sm.u384[j] = su;
    sm.v00[j]  = sv + b_ih[j];
  }
  // zero h/hh/v fully; set h/hh [:53][128]=1
  for (int idx = tid; idx < 56*132; idx += NT) {
    int r = idx/132, c = idx - r*132;
    float hv = (c == 128 && r < 53) ? 1.f : 0.f;
    sm.h[r][c] = hv; sm.hh[r][c] = hv; sm.v[r][c] = 0.f;
  }
  // zero the z/GA-GB union region
  for (int idx = tid; idx < 53*132; idx += NT) (&sm.ab.z[0][0])[idx] = 0.f;
  // zero S and G0
  for (int idx = tid; idx < 56*60; idx += NT) {
    int r = idx/60, c = idx - r*60;
    sm.S[r][c] = 0.f; sm.G0[r][c] = 0.f;
  }
  // stage gate_b in LDS (constant across all 200 steps)
  for (int idx = tid; idx < 2809; idx += NT) sm.gb[idx] = gate_b[idx];
  __syncthreads();

  const int f  = tid & 127;
  const int c0 = tid >> 7;       // 0..7
  int  cix[7]; bool cok[7];
  #pragma unroll
  for (int i = 0; i < 7; ++i) { int cc = c0 + 8*i; cok[i] = (cc < 53); cix[i] = cok[i] ? cc : 52; }

  // lane-major weight bases: per q-chunk the wave reads contiguous 1KB per plane
  const float* pw1 = Wp1 + (size_t)f*4;          // planes at +0, +16896, +33792
  const float* pw2 = Wp2 + (size_t)f*4;          // planes at +0, +16896
  const float* W256 = Wp2 + 33792;
  const int colA = 2*f, colB = colA + 1;         // phase2 col pair (0..255)

  // ---- persistent register cache: chunks 0,1 of both weight sets (40 VGPR).
  // Same values every step -> load once; removes cold-start latency in P1/P2
  // and ~24KB/step of re-fetch.
  const float4 P10a = *(const float4*)(pw1);
  const float4 P10b = *(const float4*)(pw1 + 16896);
  const float4 P10c = *(const float4*)(pw1 + 33792);
  const float4 P11a = *(const float4*)(pw1 + 512);
  const float4 P11b = *(const float4*)(pw1 + 512 + 16896);
  const float4 P11c = *(const float4*)(pw1 + 512 + 33792);
  const float4 P20a = *(const float4*)(pw2);
  const float4 P20b = *(const float4*)(pw2 + 16896);
  const float4 P21a = *(const float4*)(pw2 + 512);
  const float4 P21b = *(const float4*)(pw2 + 512 + 16896);

  float xreg = 0.f;
  if (tid < 53) xreg = x[(b*200)*53 + tid];

  for (int t = 0; t < 200; ++t) {
    if (tid < 53) sm.xt[tid] = xreg;
    __syncthreads();   // B1: x + phase-4b h writes visible
    if (tid < 53 && t < 199) xreg = x[(b*200 + t + 1)*53 + tid];  // prefetch next step

    // ---------- Phase 1: gh = h@Whh_hat (K=129, bias folded), GRU -> hh ----------
    // chunks 0,1 from persistent regs; chunks 2..32 streamed with depth-2 prefetch
    float a0[7], a1[7], a2[7];
    #pragma unroll
    for (int i = 0; i < 7; ++i) { a0[i] = 0.f; a1[i] = 0.f; a2[i] = 0.f; }
    {
      // issue stream loads for chunks 2,3 (latency covered by reg-chunk compute)
      float4 A0 = *(const float4*)(pw1 + 1024);
      float4 A1 = *(const float4*)(pw1 + 1024 + 16896);
      float4 A2 = *(const float4*)(pw1 + 1024 + 33792);
      float4 B0 = *(const float4*)(pw1 + 1536);
      float4 B1 = *(const float4*)(pw1 + 1536 + 16896);
      float4 B2 = *(const float4*)(pw1 + 1536 + 33792);
      #pragma unroll
      for (int i = 0; i < 7; ++i) {
        float4 hv = *(const float4*)&sm.h[cix[i]][0];
        acc4(a0[i], hv, P10a); acc4(a1[i], hv, P10b); acc4(a2[i], hv, P10c);
      }
      #pragma unroll
      for (int i = 0; i < 7; ++i) {
        float4 hv = *(const float4*)&sm.h[cix[i]][4];
        acc4(a0[i], hv, P11a); acc4(a1[i], hv, P11b); acc4(a2[i], hv, P11c);
      }
      for (int c = 2; c <= 30; c += 2) {
        #pragma unroll
        for (int i = 0; i < 7; ++i) {
          float4 hv = *(const float4*)&sm.h[cix[i]][4*c];
          acc4(a0[i], hv, A0); acc4(a1[i], hv, A1); acc4(a2[i], hv, A2);
        }
        if (c + 2 <= 32) {
          const float* p = pw1 + (c+2)*512;
          A0 = *(const float4*)(p); A1 = *(const float4*)(p + 16896); A2 = *(const float4*)(p + 33792);
        }
        #pragma unroll
        for (int i = 0; i < 7; ++i) {
          float4 hv = *(const float4*)&sm.h[cix[i]][4*(c+1)];
          acc4(a0[i], hv, B0); acc4(a1[i], hv, B1); acc4(a2[i], hv, B2);
        }
        if (c + 3 <= 32) {
          const float* p = pw1 + (c+3)*512;
          B0 = *(const float4*)(p); B1 = *(const float4*)(p + 16896); B2 = *(const float4*)(p + 33792);
        }
      }
      #pragma unroll
      for (int i = 0; i < 7; ++i) {
        float4 hv = *(const float4*)&sm.h[cix[i]][128];   // chunk 32
        acc4(a0[i], hv, A0); acc4(a1[i], hv, A1); acc4(a2[i], hv, A2);
      }
    }
    // pre-issue P2's stream chunks 2,3 NOW: latency hides under the GRU math
    // and the B2 barrier; they cross B2 complete.
    float4 pA0 = *(const float4*)(pw2 + 1024);
    float4 pA1 = *(const float4*)(pw2 + 1024 + 16896);
    float4 pB0 = *(const float4*)(pw2 + 1536);
    float4 pB1 = *(const float4*)(pw2 + 1536 + 16896);
    {
      float uf0 = sm.u384[f], uf1 = sm.u384[128+f], uf2 = sm.u384[256+f];
      float v0f0 = sm.v00[f], v0f1 = sm.v00[128+f], v0f2 = sm.v00[256+f];
      #pragma unroll
      for (int i = 0; i < 7; ++i) {
        float xs = sm.xt[cix[i]];
        float r = fast_sigmoid(fmaf(xs, uf0, v0f0) + a0[i]);
        float z = fast_sigmoid(fmaf(xs, uf1, v0f1) + a1[i]);
        float n = fast_tanh(fmaf(xs, uf2, v0f2) + fmaf(r, a2[i], 0.f));
        float hn = (1.f - z)*n + z*sm.h[cix[i]][f];
        if (cok[i]) sm.hh[cix[i]][f] = hn;   // write to hh: no hazard vs h reads
      }
    }
    __syncthreads();   // B2: hh (hhat) complete

    // ---------- Phase 2: [z|v] = hh @ WT^T  (257 cols, K=129) ----------
    {
      float aA[7], aB[7];
      #pragma unroll
      for (int i = 0; i < 7; ++i) { aA[i] = 0.f; aB[i] = 0.f; }
      #pragma unroll
      for (int i = 0; i < 7; ++i) {
        float4 hv = *(const float4*)&sm.hh[cix[i]][0];
        acc4(aA[i], hv, P20a); acc4(aB[i], hv, P20b);
      }
      #pragma unroll
      for (int i = 0; i < 7; ++i) {
        float4 hv = *(const float4*)&sm.hh[cix[i]][4];
        acc4(aA[i], hv, P21a); acc4(aB[i], hv, P21b);
      }
      for (int c = 2; c <= 30; c += 2) {
        #pragma unroll
        for (int i = 0; i < 7; ++i) {
          float4 hv = *(const float4*)&sm.hh[cix[i]][4*c];
          acc4(aA[i], hv, pA0); acc4(aB[i], hv, pA1);
        }
        if (c + 2 <= 32) {
          const float* p = pw2 + (c+2)*512;
          pA0 = *(const float4*)(p); pA1 = *(const float4*)(p + 16896);
        }
        #pragma unroll
        for (int i = 0; i < 7; ++i) {
          float4 hv = *(const float4*)&sm.hh[cix[i]][4*(c+1)];
          acc4(aA[i], hv, pB0); acc4(aB[i], hv, pB1);
        }
        if (c + 3 <= 32) {
          const float* p = pw2 + (c+3)*512;
          pB0 = *(const float4*)(p); pB1 = *(const float4*)(p + 16896);
        }
      }
      #pragma unroll
      for (int i = 0; i < 7; ++i) {
        float4 hv = *(const float4*)&sm.hh[cix[i]][128];   // chunk 32
        acc4(aA[i], hv, pA0); acc4(aB[i], hv, pA1);
      }
      #pragma unroll
      for (int i = 0; i < 7; ++i) if (cok[i]) {
        int c = cix[i];
        if (colA < 129) sm.ab.z[c][colA] = aA[i]; else sm.v[c][colA-129] = aA[i];
        if (colB < 129) sm.ab.z[c][colB] = aB[i]; else sm.v[c][colB-129] = aB[i];
      }
      // col 256 = v[:,127]
      if (tid < 53) {
        float s = 0.f;
        for (int q = 0; q < 33; ++q) {
          float4 wv4 = *(const float4*)(W256 + 4*q);
          float4 hv = *(const float4*)&sm.hh[tid][4*q];
          acc4(s, hv, wv4);
        }
        sm.v[tid][127] = s;
      }
    }
    __syncthreads();   // B3: z, v ready

    // ---------- Phase 3: S = tanh(z @ hh^T)  (K=129); zero gmax ----------
    // z cols 129..131 may hold stale GA/GB data but multiply hh[*][129..131]==0.
    if (tid < 9) sm.gmax[tid] = 0;
    if (wv < 14 && lane < 53) {
      const int i = lane, j0 = 4*wv;
      float4 acc; acc.x = acc.y = acc.z = acc.w = 0.f;
      for (int q = 0; q < 33; ++q) {
        float4 zr = *(const float4*)&sm.ab.z[i][4*q];
        float4 h0 = *(const float4*)&sm.hh[j0  ][4*q];
        float4 h1 = *(const float4*)&sm.hh[j0+1][4*q];
        float4 h2 = *(const float4*)&sm.hh[j0+2][4*q];
        float4 h3 = *(const float4*)&sm.hh[j0+3][4*q];
        acc4(acc.x, zr, h0); acc4(acc.y, zr, h1); acc4(acc.z, zr, h2); acc4(acc.w, zr, h3);
      }
      sm.S[i][j0  ] = fast_tanh(acc.x);
      sm.S[i][j0+1] = fast_tanh(acc.y);
      sm.S[i][j0+2] = fast_tanh(acc.z);
      sm.S[i][j0+3] = fast_tanh(acc.w);
    }
    __syncthreads();   // B4: S ready; z dead -> GA/GB live

    // ---------- G0 = S @ S^T (symmetric), fused max; waves 14/15 zero GA/GB pads ----------
    {
      float mx = 0.f;
      if (wv < 14 && lane < 53) {
        const int i = lane, j0 = 4*wv;
        float4 acc; acc.x = acc.y = acc.z = acc.w = 0.f;
        for (int q = 0; q < 14; ++q) {
          float4 sr = *(const float4*)&sm.S[i][4*q];
          float4 s0 = *(const float4*)&sm.S[j0  ][4*q];
          float4 s1 = *(const float4*)&sm.S[j0+1][4*q];
          float4 s2 = *(const float4*)&sm.S[j0+2][4*q];
          float4 s3 = *(const float4*)&sm.S[j0+3][4*q];
          acc4(acc.x, sr, s0); acc4(acc.y, sr, s1); acc4(acc.z, sr, s2); acc4(acc.w, sr, s3);
        }
        sm.G0[i][j0] = acc.x; sm.G0[i][j0+1] = acc.y;
        sm.G0[i][j0+2] = acc.z; sm.G0[i][j0+3] = acc.w;
        mx = fmaxf(fmaxf(fabsf(acc.x), fabsf(acc.y)), fmaxf(fabsf(acc.z), fabsf(acc.w)));
      }
      if (wv < 14) {
        for (int off = 32; off; off >>= 1) mx = fmaxf(mx, __shfl_down(mx, off));
        if (lane == 0) atomicMax(&sm.gmax[0], __float_as_int(mx));
      } else {
        // re-zero GA/GB pad rows 53..55 (clobbered by z writes this step)
        float* GAB = &sm.ab.G[0][0][0];
        for (int l = tid - 896; l < 180; l += 128) {
          GAB[3180 + l] = 0.f;        // GA rows 53..55
          GAB[6540 + l] = 0.f;        // GB rows 53..55
        }
      }
    }
    __syncthreads();

    // ---------- 7 normalized squarings of symmetric matrix ----------
    float (*pa)[60] = sm.G0;
    float (*pc)[60] = sm.ab.G[0];
    for (int k = 0; k < 7; ++k) {
      float mx = 0.f;
      if (wv < 14 && lane < 53) {
        float s = 1.f/fmaxf(__int_as_float(sm.gmax[k]), 1e-20f);
        const int i = lane, j0 = 4*wv;
        float4 acc; acc.x = acc.y = acc.z = acc.w = 0.f;
        for (int q = 0; q < 14; ++q) {
          float4 ar = *(const float4*)&pa[i][4*q];
          float4 b0 = *(const float4*)&pa[j0  ][4*q];
          float4 b1 = *(const float4*)&pa[j0+1][4*q];
          float4 b2 = *(const float4*)&pa[j0+2][4*q];
          float4 b3 = *(const float4*)&pa[j0+3][4*q];
          acc4(acc.x, ar, b0); acc4(acc.y, ar, b1); acc4(acc.z, ar, b2); acc4(acc.w, ar, b3);
        }
        float s2 = s*s;
        acc.x *= s2; acc.y *= s2; acc.z *= s2; acc.w *= s2;
        pc[i][j0] = acc.x; pc[i][j0+1] = acc.y; pc[i][j0+2] = acc.z; pc[i][j0+3] = acc.w;
        mx = fmaxf(fmaxf(fabsf(acc.x), fabsf(acc.y)), fmaxf(fabsf(acc.z), fabsf(acc.w)));
      }
      if (wv < 14) {
        for (int off = 32; off; off >>= 1) mx = fmaxf(mx, __shfl_down(mx, off));
        if (lane == 0) atomicMax(&sm.gmax[k+1], __float_as_int(mx));
      }
      __syncthreads();
      float (*tn)[60] = pc;
      pc = (pc == sm.ab.G[0]) ? sm.ab.G[1] : sm.ab.G[0];
      pa = tn;
    }
    // pa == sm.ab.G[0] (final power-iterated matrix)

    // ---------- Rayleigh tail: wave 0 only, in-wave LDS ordering (no barriers) ----------
    if (wv == 0) {
      if (lane < 53) {
        float s = 0.f;
        for (int j = 0; j < 53; ++j) {
          float ph = 0.618034f*(float)(j + 1);
          float rj = 0.75f + 0.5f*(ph - floorf(ph));
          s = fmaf(pa[j][lane], rj, s);
        }
        sm.pv[lane] = s;
      }
      __builtin_amdgcn_sched_barrier(0);
      if (lane < 53) {
        float s = 0.f;
        for (int j = 0; j < 53; ++j) s = fmaf(sm.G0[j][lane], sm.pv[j], s);
        sm.y1[lane] = s;
      }
      __builtin_amdgcn_sched_barrier(0);
      if (lane < 53) {
        float s = 0.f;
        for (int j = 0; j < 53; ++j) s = fmaf(sm.G0[j][lane], sm.y1[j], s);
        sm.y2[lane] = s;
      }
      __builtin_amdgcn_sched_barrier(0);
      float y3v = 0.f, y2v = 0.f;
      if (lane < 53) {
        float s = 0.f;
        for (int j = 0; j < 53; ++j) s = fmaf(sm.G0[j][lane], sm.y2[j], s);
        y3v = s; y2v = sm.y2[lane];
      }
      float num = y2v*y3v, den = y2v*y2v;
      for (int off = 32; off; off >>= 1) { num += __shfl_down(num, off); den += __shfl_down(den, off); }
      if (lane == 0) sm.sc_ev = sqrtf(num/fmaxf(den, 1e-30f));
    }
    __syncthreads();   // sc_ev visible

    // ---------- Phase 4a: attn = (S/ev)*sigmoid(|S/ev| + gate_b); write align ----------
    {
      float inv = 1.f/sm.sc_ev;
      const size_t abase = ((size_t)b*200 + (size_t)t)*2809;
      for (int idx = tid; idx < 2809; idx += NT) {
        int i = idx/53, j = idx - i*53;
        float s = sm.S[i][j]*inv;
        float a = s*fast_sigmoid(fabsf(s) + sm.gb[idx]);
        sm.S[i][j] = a;
        __builtin_nontemporal_store(a, &out_align[abase + idx]);
      }
    }
    __syncthreads();   // S rescaled

    // ---------- Phase 4b: h <- attn @ v (writes h cols 0..127; next step's input) ----------
    {
      const int f0 = (tid & 31)*4;
      const int io = tid >> 5;           // 0..31
      const int i1 = io + 32;
      const bool has1 = (i1 < 53);
      float4 acc0, acc1;
      acc0.x = acc0.y = acc0.z = acc0.w = 0.f;
      acc1 = acc0;
      for (int q = 0; q < 14; ++q) {
        float4 s0 = *(const float4*)&sm.S[io][4*q];
        float4 s1 = *(const float4*)&sm.S[has1 ? i1 : 0][4*q];
        int j = 4*q;
        float4 v0 = *(const float4*)&sm.v[j  ][f0];
        float4 v1 = *(const float4*)&sm.v[j+1][f0];
        float4 v2 = *(const float4*)&sm.v[j+2][f0];
        float4 v3 = *(const float4*)&sm.v[j+3][f0];
        FMA4(acc0, s0.x, v0); FMA4(acc0, s0.y, v1); FMA4(acc0, s0.z, v2); FMA4(acc0, s0.w, v3);
        FMA4(acc1, s1.x, v0); FMA4(acc1, s1.y, v1); FMA4(acc1, s1.z, v2); FMA4(acc1, s1.w, v3);
      }
      *(float4*)&sm.h[io][f0] = acc0;
      if (has1) *(float4*)&sm.h[i1][f0] = acc1;
      // next-iteration B1 synchronizes these writes
    }
  }
}

// ---------------- post-scan kernels (unchanged) ----------------

__global__ void mean_kernel(const float* __restrict__ align, float* __restrict__ m) {
  int idx = blockIdx.x*256 + threadIdx.x;
  if (idx >= 64*2809) return;
  int b = idx/2809, c = idx - b*2809;
  const float* p = align + (size_t)b*200*2809 + c;
  float s = 0.f;
  for (int t = 0; t < 200; ++t) s += p[(size_t)t*2809];
  m[idx] = s*(1.f/200.f);
}

__global__ void __launch_bounds__(256) xe_kernel(const float* __restrict__ align,
    const float* __restrict__ mai, const float* __restrict__ ge_w,
    const float* __restrict__ ge_b, float* __restrict__ xe) {
  __shared__ float sai[8][64];
  __shared__ float sw[64][140];
  const int tid = threadIdx.x;
  const int r0 = blockIdx.x*8;
  float4 acc0, acc1;
  acc0.x = acc0.y = acc0.z = acc0.w = 0.f;
  acc1 = acc0;
  const bool active = tid < 140;
  int rr0 = 0, cc0 = 0;
  if (active) { rr0 = (tid/35)*2; cc0 = (tid - 35*(tid/35))*4; }
  for (int k0 = 0; k0 < 2809; k0 += 64) {
    for (int l = tid; l < 512; l += 256) {
      int rr = l >> 6, kk = l & 63, k = k0 + kk;
      int r = r0 + rr;
      int bb = r/200;
      sai[rr][kk] = (k < 2809) ? align[(size_t)r*2809 + k]*mai[bb*2809 + k] : 0.f;
    }
    for (int l = tid; l < 64*140; l += 256) {
      int kk = l/140, cc = l - kk*140, k = k0 + kk;
      sw[kk][cc] = (k < 2809) ? ge_w[k*140 + cc] : 0.f;
    }
    __syncthreads();
    if (active) {
      for (int kk = 0; kk < 64; ++kk) {
        float a0 = sai[rr0][kk], a1 = sai[rr0+1][kk];
        float4 wv = *(const float4*)&sw[kk][cc0];
        FMA4(acc0, a0, wv); FMA4(acc1, a1, wv);
      }
    }
    __syncthreads();
  }
  if (active) {
    float4 gb = *(const float4*)&ge_b[cc0];
    acc0.x += gb.x; acc0.y += gb.y; acc0.z += gb.z; acc0.w += gb.w;
    acc1.x += gb.x; acc1.y += gb.y; acc1.z += gb.z; acc1.w += gb.w;
    *(float4*)&xe[(r0 + rr0)*140 + cc0]   = acc0;
    *(float4*)&xe[(r0 + rr0 + 1)*140 + cc0] = acc1;
  }
}

__global__ void bn_stats_kernel(const float* __restrict__ xe, float* __restrict__ mu,
                                float* __restrict__ var) {
  const int c = blockIdx.x, tid = threadIdx.x;
  double s = 0.0, sq = 0.0;
  for (int r = tid; r < 12800; r += 256) {
    double v = (double)xe[r*140 + c];
    s += v; sq += v*v;
  }
  for (int off = 32; off; off >>= 1) { s += __shfl_down(s, off); sq += __shfl_down(sq, off); }
  __shared__ double rs[4], rq[4];
  if ((tid & 63) == 0) { rs[tid >> 6] = s; rq[tid >> 6] = sq; }
  __syncthreads();
  if (tid == 0) {
    double S = rs[0]+rs[1]+rs[2]+rs[3], Q = rq[0]+rq[1]+rq[2]+rq[3];
    double m = S/12800.0;
    double v = Q/12800.0 - m*m;
    mu[c] = (float)m;
    var[c] = (float)fmax(v, 0.0);
  }
}

__global__ void __launch_bounds__(256) a_kernel(const float* __restrict__ xe,
    const float* __restrict__ mu, const float* __restrict__ var,
    const float* __restrict__ bn_g, const float* __restrict__ bn_b,
    const float* __restrict__ ga_w1, const float* __restrict__ ga_b1,
    const float* __restrict__ ga_w2, const float* __restrict__ ga_b2,
    float* __restrict__ a_out) {
  __shared__ float sxn[16][140];
  __shared__ float rsum[16];
  const int tid = threadIdx.x;
  const int r0 = blockIdx.x*16;
  for (int l = tid; l < 16*140; l += 256) {
    int rr = l/140, cc = l - rr*140;
    float v = xe[(r0 + rr)*140 + cc];
    float xn = (v - mu[cc])*rsqrtf(var[cc] + 1e-5f)*bn_g[cc] + bn_b[cc];
    sxn[rr][cc] = fmaxf(xn, 0.f);
  }
  if (tid < 16) rsum[tid] = 0.f;
  __syncthreads();
  float asum[16];
  #pragma unroll
  for (int r = 0; r < 16; ++r) asum[r] = 0.f;
  for (int j = tid; j < 1404; j += 256) {
    float acc[16];
    #pragma unroll
    for (int r = 0; r < 16; ++r) acc[r] = 0.f;
    for (int k = 0; k < 140; ++k) {
      float wv = ga_w1[k*1404 + j];
      #pragma unroll
      for (int r = 0; r < 16; ++r) acc[r] += sxn[r][k]*wv;
    }
    float b1 = ga_b1[j], w2 = ga_w2[j];
    #pragma unroll
    for (int r = 0; r < 16; ++r) asum[r] += fmaxf(acc[r] + b1, 0.f)*w2;
  }
  #pragma unroll
  for (int r = 0; r < 16; ++r) atomicAdd(&rsum[r], asum[r]);
  __syncthreads();
  if (tid < 16) a_out[r0 + tid] = rsum[tid] + ga_b2[0];
}

__global__ void softmax_kernel(const float* __restrict__ a, float* __restrict__ w) {
  const int b = blockIdx.x, tid = threadIdx.x;  // 64 threads
  float mx = -1e30f;
  for (int t = tid; t < 200; t += 64) mx = fmaxf(mx, a[b*200 + t]);
  for (int off = 32; off; off >>= 1) mx = fmaxf(mx, __shfl_down(mx, off));
  mx = __shfl(mx, 0);
  float s = 0.f;
  for (int t = tid; t < 200; t += 64) { float e = __expf(a[b*200 + t] - mx); w[b*200 + t] = e; s += e; }
  for (int off = 32; off; off >>= 1) s += __shfl_down(s, off);
  s = __shfl(s, 0);
  float inv = 1.f/s;
  for (int t = tid; t < 200; t += 64) w[b*200 + t] *= inv;
}

__global__ void dnc_kernel(const float* __restrict__ align, const float* __restrict__ w,
                           float* __restrict__ dnc) {
  int idx = blockIdx.x*256 + threadIdx.x;
  if (idx >= 64*2809) return;
  int b = idx/2809, c = idx - b*2809;
  const float* p = align + (size_t)b*200*2809 + c;
  const float* pw = w + b*200;
  float s = 0.f;
  for (int t = 0; t < 200; ++t) s += p[(size_t)t*2809]*pw[t];
  dnc[idx] = s;
}

__global__ void fc_relu_kernel(const float* __restrict__ in, const float* __restrict__ wgt,
    const float* __restrict__ bias, float* __restrict__ out, int rows, int K, int N) {
  int idx = blockIdx.x*256 + threadIdx.x;
  if (idx >= rows*N) return;
  int r = idx/N, j = idx - r*N;
  const float* pi = in + (size_t)r*K;
  float s = 0.f;
  for (int k = 0; k < K; ++k) s += pi[k]*wgt[k*N + j];
  out[idx] = fmaxf(s + bias[j], 0.f);
}

__global__ void fc_kernel(const float* __restrict__ in, const float* __restrict__ wgt,
    const float* __restrict__ bias, float* __restrict__ out, int rows, int K, int N) {
  int idx = blockIdx.x*256 + threadIdx.x;
  if (idx >= rows*N) return;
  int r = idx/N, j = idx - r*N;
  const float* pi = in + (size_t)r*K;
  float s = 0.f;
  for (int k = 0; k < K; ++k) s += pi[k]*wgt[k*N + j];
  out[idx] = s + bias[j];
}

extern "C" void kernel_launch(void* const* d_in, const int* in_sizes, int n_in,
                              void* d_out, int out_size, void* d_ws, size_t ws_size,
                              hipStream_t stream) {
  (void)in_sizes; (void)n_in; (void)out_size; (void)ws_size;
  const float* x      = (const float*)d_in[0];
  const float* emb_w  = (const float*)d_in[1];
  const float* emb_b  = (const float*)d_in[2];
  const float* w_ih   = (const float*)d_in[3];
  const float* w_hh   = (const float*)d_in[4];
  const float* b_ih   = (const float*)d_in[5];
  const float* b_hh   = (const float*)d_in[6];
  const float* q_w    = (const float*)d_in[7];
  const float* q_b    = (const float*)d_in[8];
  const float* k_w    = (const float*)d_in[9];
  const float* k_b    = (const float*)d_in[10];
  const float* v_w    = (const float*)d_in[11];
  const float* v_b    = (const float*)d_in[12];
  const float* gate_b = (const float*)d_in[13];
  const float* ge_w   = (const float*)d_in[14];
  const float* ge_b   = (const float*)d_in[15];
  const float* bn_g   = (const float*)d_in[16];
  const float* bn_b   = (const float*)d_in[17];
  const float* ga_w1  = (const float*)d_in[18];
  const float* ga_b1  = (const float*)d_in[19];
  const float* ga_w2  = (const float*)d_in[20];
  const float* ga_b2  = (const float*)d_in[21];
  const float* c_w1   = (const float*)d_in[22];
  const float* c_b1   = (const float*)d_in[23];
  const float* c_w2   = (const float*)d_in[24];
  const float* c_b2   = (const float*)d_in[25];
  const float* c_w3   = (const float*)d_in[26];
  const float* c_b3   = (const float*)d_in[27];

  float* out = (float*)d_out;
  float* out_logits = out;                    // 128
  float* out_dnc    = out + 128;              // 64*2809
  float* out_align  = out + 128 + 64*2809;    // 64*200*2809

  float* ws    = (float*)d_ws;
  float* w_Wp1 = ws;                          // 50688
  float* w_Wp2 = w_Wp1 + 50688;               // 33924
  float* w_m   = w_Wp2 + 33924;               // 179776
  float* w_xe  = w_m + 179776;                // 1792000
  float* w_mu  = w_xe + 1792000;              // 140
  float* w_var = w_mu + 140;                  // 140
  float* w_a   = w_var + 140;                 // 12800
  float* w_w   = w_a + 12800;                 // 12800
  float* w_h1  = w_w + 12800;                 // 89856
  float* w_h2  = w_h1 + 89856;                // 44928

  hipLaunchKernelGGL(prep_wp1, dim3((50688 + 255)/256), dim3(256), 0, stream, w_hh, b_hh, w_Wp1);
  hipLaunchKernelGGL(prep_wp2, dim3((33924 + 255)/256), dim3(256), 0, stream,
                     q_w, q_b, k_w, k_b, v_w, v_b, w_Wp2);

  const size_t shmem = sizeof(SmemScan);
  (void)hipFuncSetAttribute(reinterpret_cast<const void*>(scan_kernel),
                            hipFuncAttributeMaxDynamicSharedMemorySize, (int)shmem);

  hipLaunchKernelGGL(scan_kernel, dim3(64), dim3(1024), shmem, stream,
                     x, emb_w, emb_b, w_ih, b_ih, w_Wp1, w_Wp2, gate_b, out_align);

  hipLaunchKernelGGL(mean_kernel, dim3(703), dim3(256), 0, stream, out_align, w_m);
  hipLaunchKernelGGL(xe_kernel, dim3(1600), dim3(256), 0, stream, out_align, w_m, ge_w, ge_b, w_xe);
  hipLaunchKernelGGL(bn_stats_kernel, dim3(140), dim3(256), 0, stream, w_xe, w_mu, w_var);
  hipLaunchKernelGGL(a_kernel, dim3(800), dim3(256), 0, stream,
                     w_xe, w_mu, w_var, bn_g, bn_b, ga_w1, ga_b1, ga_w2, ga_b2, w_a);
  hipLaunchKernelGGL(softmax_kernel, dim3(64), dim3(64), 0, stream, w_a, w_w);
  hipLaunchKernelGGL(dnc_kernel, dim3(703), dim3(256), 0, stream, out_align, w_w, out_dnc);
  hipLaunchKernelGGL(fc_relu_kernel, dim3(351), dim3(256), 0, stream, out_dnc, c_w1, c_b1, w_h1, 64, 2809, 1404);
  hipLaunchKernelGGL(fc_relu_kernel, dim3(176), dim3(256), 0, stream, w_h1, c_w2, c_b2, w_h2, 64, 1404, 702);
  hipLaunchKernelGGL(fc_kernel, dim3(1), dim3(128), 0, stream, w_h2, c_w3, c_b3, out_logits, 64, 702, 2);
}

// Round 7
// 29789.941 us; speedup vs baseline: 1.1797x; 1.1797x over previous
//
#include <hip/hip_runtime.h>

#define NT 1024

typedef __attribute__((ext_vector_type(8))) short bf16x8;
typedef __attribute__((ext_vector_type(4))) float f32x4;

__device__ __forceinline__ float fast_sigmoid(float x) { return 1.f/(1.f + __expf(-x)); }
__device__ __forceinline__ float fast_tanh(float x) {
  float t = __expf(-2.f*fabsf(x));
  float y = (1.f - t)/(1.f + t);
  return copysignf(y, x);
}
__device__ __forceinline__ void acc4(float& a, float4 u, float4 v) {
  a = fmaf(u.x, v.x, a); a = fmaf(u.y, v.y, a); a = fmaf(u.z, v.z, a); a = fmaf(u.w, v.w, a);
}
// fp32 -> bf16 round-to-nearest-even
__device__ __forceinline__ unsigned short bf16r(float x) {
  unsigned int u = __float_as_uint(x);
  u += 0x7FFFu + ((u >> 16) & 1u);
  return (unsigned short)(u >> 16);
}
#define FMA4(A_, S_, V_) do { (A_).x = fmaf((S_),(V_).x,(A_).x); (A_).y = fmaf((S_),(V_).y,(A_).y); \
                              (A_).z = fmaf((S_),(V_).z,(A_).z); (A_).w = fmaf((S_),(V_).w,(A_).w); } while(0)

// ~155 KB LDS. Round-5 structure; the squaring ping-pong buffers are replaced by
// a single bf16 matrix Abf[64][80] (10 KB) aliasing dead z:
//  - z written in P2, read in P3 (dead after B4). Abf written in the G0 phase
//    (bf16 of G0) and during squarings; read until pv. Next-step P2 rewrites z.
//  - Abf row stride 80 bf16 = 160 B (4-way bank pattern on fragment reads).
struct alignas(16) SmemScan {
  float h[56][132];     // step-input h; col 128 == 1.0 (bias folding); pads 0
  float hh[56][132];    // hhat = GRU output; col 128 == 1.0; pads 0
  float v[56][132];
  union {
    float z[53][132];             // phase-2 output, read in phase 3, dead after B4
    unsigned short Abf[64][80];   // bf16 squaring state (padded 53->64, stride 80)
  } ab;
  float S[56][60];
  float G0[56][60];
  float u384[384], v00[384];
  float gb[2812];       // gate_b cached (constant)
  float xt[56];
  float pv[56], y1[56], y2[56];
  int   gmax[9];
  float sc_ev;
};

// ---------------- prep kernels (run once per launch) ----------------
// Lane-major repack of the GRU hidden weights:
//   Wp1[((g*33 + q)*128 + f)*4 + j] = Whh_hat[4q+j][g*128+f]
__global__ void prep_wp1(const float* __restrict__ w_hh, const float* __restrict__ b_hh,
                         float* __restrict__ Wp1) {
  int idx = blockIdx.x*256 + threadIdx.x;
  if (idx >= 3*33*128*4) return;            // 50688
  int j = idx & 3;
  int f = (idx >> 2) & 127;
  int qg = idx >> 9;
  int q = qg % 33;
  int g = qg / 33;
  int k = 4*q + j;
  int col = g*128 + f;
  float v = 0.f;
  if (k < 128) v = w_hh[k*384 + col];
  else if (k == 128) v = b_hh[col];
  Wp1[idx] = v;
}

// Lane-major repack of the fused attention weights.
__global__ void prep_wp2(const float* __restrict__ q_w, const float* __restrict__ q_b,
                         const float* __restrict__ k_w, const float* __restrict__ k_b,
                         const float* __restrict__ v_w, const float* __restrict__ v_b,
                         float* __restrict__ Wp2) {
  int idx = blockIdx.x*256 + threadIdx.x;
  if (idx >= 33924) return;                 // 2*33*128*4 + 132
  float val = 0.f;
  if (idx < 33792) {
    int j = idx & 3;
    int f = (idx >> 2) & 127;
    int qp = idx >> 9;
    int q = qp % 33;
    int p = qp / 33;
    int u = 2*f + p;                        // 0..255
    int k = 4*q + j;                        // 0..131
    if (u < 129) {
      if (k <= 128) {
        const float* qa = (k < 128) ? (q_w + k*128) : q_b;
        const float* kb = (u < 128) ? (k_w + u*128) : k_b;
        float s = 0.f;
        for (int d = 0; d < 128; ++d) s = fmaf(qa[d], kb[d], s);
        val = s;
      }
    } else {
      int f2 = u - 129;
      if (k < 128) val = v_w[k*128 + f2];
      else if (k == 128) val = v_b[f2];
    }
  } else {
    int c = idx - 33792;                    // W256[c]
    if (c < 128) val = v_w[c*128 + 127];
    else if (c == 128) val = v_b[127];
  }
  Wp2[idx] = val;
}

// ---------------- main scan kernel: one block per batch ----------------
__global__ void __launch_bounds__(1024, 4)
scan_kernel(const float* __restrict__ x, const float* __restrict__ emb_w,
            const float* __restrict__ emb_b, const float* __restrict__ w_ih,
            const float* __restrict__ b_ih, const float* __restrict__ Wp1,
            const float* __restrict__ Wp2, const float* __restrict__ gate_b,
            float* __restrict__ out_align)
{
  extern __shared__ char smem_raw[];
  SmemScan& sm = *reinterpret_cast<SmemScan*>(smem_raw);
  const int b = blockIdx.x;
  const int tid = threadIdx.x;
  const int wv = tid >> 6;
  const int lane = tid & 63;

  // ---- setup: u384 = emb_w@w_ih, v00 = emb_b@w_ih + b_ih ----
  for (int j = tid; j < 384; j += NT) {
    float su = 0.f, sv = 0.f;
    for (int m = 0; m < 64; ++m) {
      float w = w_ih[m*384 + j];
      su = fmaf(emb_w[m], w, su);
      sv = fmaf(emb_b[m], w, sv);
    }
    sm.u384[j] = su;
    sm.v00[j]  = sv + b_ih[j];
  }
  // zero h/hh/v fully; set h/hh [:53][128]=1
  for (int idx = tid; idx < 56*132; idx += NT) {
    int r = idx/132, c = idx - r*132;
    float hv = (c == 128 && r < 53) ? 1.f : 0.f;
    sm.h[r][c] = hv; sm.hh[r][c] = hv; sm.v[r][c] = 0.f;
  }
  // zero the z/Abf union region
  for (int idx = tid; idx < 53*132; idx += NT) (&sm.ab.z[0][0])[idx] = 0.f;
  // zero S and G0
  for (int idx = tid; idx < 56*60; idx += NT) {
    int r = idx/60, c = idx - r*60;
    sm.S[r][c] = 0.f; sm.G0[r][c] = 0.f;
  }
  // stage gate_b in LDS (constant across all 200 steps)
  for (int idx = tid; idx < 2809; idx += NT) sm.gb[idx] = gate_b[idx];
  __syncthreads();

  const int f  = tid & 127;
  const int c0 = tid >> 7;       // 0..7
  int  cix[7]; bool cok[7];
  #pragma unroll
  for (int i = 0; i < 7; ++i) { int cc = c0 + 8*i; cok[i] = (cc < 53); cix[i] = cok[i] ? cc : 52; }

  // lane-major weight bases: per q-chunk the wave reads contiguous 1KB per plane
  const float* pw1 = Wp1 + (size_t)f*4;          // planes at +0, +16896, +33792
  const float* pw2 = Wp2 + (size_t)f*4;          // planes at +0, +16896
  const float* W256 = Wp2 + 33792;
  const int colA = 2*f, colB = colA + 1;         // phase2 col pair (0..255)

  // MFMA tile assignment for the squaring chain: wave -> 16x16 tile (tr, tc)
  const int tr = wv >> 2, tc = wv & 3;
  const int frow = lane & 15;                    // fragment row within tile
  const int fkb  = (lane >> 4) * 16;             // fragment k-block byte offset

  float xreg = 0.f;
  if (tid < 53) xreg = x[(b*200)*53 + tid];

  for (int t = 0; t < 200; ++t) {
    if (tid < 53) sm.xt[tid] = xreg;
    __syncthreads();   // B1: x + phase-4b h writes visible
    if (tid < 53 && t < 199) xreg = x[(b*200 + t + 1)*53 + tid];  // prefetch next step

    // ---------- Phase 1: gh = h@Whh_hat (K=129, bias folded), GRU -> hh ----------
    // double-buffered weight prefetch (depth 1, fits 64 VGPR — round-2/5 proven)
    float a0[7], a1[7], a2[7];
    #pragma unroll
    for (int i = 0; i < 7; ++i) { a0[i] = 0.f; a1[i] = 0.f; a2[i] = 0.f; }
    {
      float4 w0 = *(const float4*)(pw1);
      float4 w1 = *(const float4*)(pw1 + 16896);
      float4 w2 = *(const float4*)(pw1 + 33792);
      for (int q = 0; q < 33; ++q) {
        float4 n0 = w0, n1 = w1, n2 = w2;
        if (q < 32) {
          const float* p = pw1 + (q+1)*512;
          n0 = *(const float4*)(p);
          n1 = *(const float4*)(p + 16896);
          n2 = *(const float4*)(p + 33792);
        }
        #pragma unroll
        for (int i = 0; i < 7; ++i) {
          float4 hv = *(const float4*)&sm.h[cix[i]][4*q];
          acc4(a0[i], hv, w0); acc4(a1[i], hv, w1); acc4(a2[i], hv, w2);
        }
        w0 = n0; w1 = n1; w2 = n2;
      }
    }
    {
      float uf0 = sm.u384[f], uf1 = sm.u384[128+f], uf2 = sm.u384[256+f];
      float v0f0 = sm.v00[f], v0f1 = sm.v00[128+f], v0f2 = sm.v00[256+f];
      #pragma unroll
      for (int i = 0; i < 7; ++i) {
        float xs = sm.xt[cix[i]];
        float r = fast_sigmoid(fmaf(xs, uf0, v0f0) + a0[i]);
        float z = fast_sigmoid(fmaf(xs, uf1, v0f1) + a1[i]);
        float n = fast_tanh(fmaf(xs, uf2, v0f2) + fmaf(r, a2[i], 0.f));
        float hn = (1.f - z)*n + z*sm.h[cix[i]][f];
        if (cok[i]) sm.hh[cix[i]][f] = hn;   // write to hh: no hazard vs h reads
      }
    }
    __syncthreads();   // B2: hh (hhat) complete

    // ---------- Phase 2: [z|v] = hh @ WT^T  (257 cols, K=129) ----------
    {
      float aA[7], aB[7];
      #pragma unroll
      for (int i = 0; i < 7; ++i) { aA[i] = 0.f; aB[i] = 0.f; }
      float4 wa = *(const float4*)(pw2);
      float4 wb = *(const float4*)(pw2 + 16896);
      for (int q = 0; q < 33; ++q) {
        float4 na = wa, nb = wb;
        if (q < 32) {
          const float* p = pw2 + (q+1)*512;
          na = *(const float4*)(p);
          nb = *(const float4*)(p + 16896);
        }
        #pragma unroll
        for (int i = 0; i < 7; ++i) {
          float4 hv = *(const float4*)&sm.hh[cix[i]][4*q];
          acc4(aA[i], hv, wa); acc4(aB[i], hv, wb);
        }
        wa = na; wb = nb;
      }
      #pragma unroll
      for (int i = 0; i < 7; ++i) if (cok[i]) {
        int c = cix[i];
        if (colA < 129) sm.ab.z[c][colA] = aA[i]; else sm.v[c][colA-129] = aA[i];
        if (colB < 129) sm.ab.z[c][colB] = aB[i]; else sm.v[c][colB-129] = aB[i];
      }
      // col 256 = v[:,127]
      if (tid < 53) {
        float s = 0.f;
        for (int q = 0; q < 33; ++q) {
          float4 wv4 = *(const float4*)(W256 + 4*q);
          float4 hv = *(const float4*)&sm.hh[tid][4*q];
          acc4(s, hv, wv4);
        }
        sm.v[tid][127] = s;
      }
    }
    __syncthreads();   // B3: z, v ready

    // ---------- Phase 3: S = tanh(z @ hh^T)  (K=129); zero gmax ----------
    // z cols 129..131 may hold stale data but multiply hh[*][129..131]==0.
    if (tid < 9) sm.gmax[tid] = 0;
    if (wv < 14 && lane < 53) {
      const int i = lane, j0 = 4*wv;
      float4 acc; acc.x = acc.y = acc.z = acc.w = 0.f;
      for (int q = 0; q < 33; ++q) {
        float4 zr = *(const float4*)&sm.ab.z[i][4*q];
        float4 h0 = *(const float4*)&sm.hh[j0  ][4*q];
        float4 h1 = *(const float4*)&sm.hh[j0+1][4*q];
        float4 h2 = *(const float4*)&sm.hh[j0+2][4*q];
        float4 h3 = *(const float4*)&sm.hh[j0+3][4*q];
        acc4(acc.x, zr, h0); acc4(acc.y, zr, h1); acc4(acc.z, zr, h2); acc4(acc.w, zr, h3);
      }
      sm.S[i][j0  ] = fast_tanh(acc.x);
      sm.S[i][j0+1] = fast_tanh(acc.y);
      sm.S[i][j0+2] = fast_tanh(acc.z);
      sm.S[i][j0+3] = fast_tanh(acc.w);
    }
    __syncthreads();   // B4: S ready; z dead -> Abf live

    // ---------- G0 = S @ S^T (fp32, fused max) + emit bf16(G0) into Abf ----------
    {
      float mx = 0.f;
      if (wv < 14 && lane < 53) {
        const int i = lane, j0 = 4*wv;
        float4 acc; acc.x = acc.y = acc.z = acc.w = 0.f;
        for (int q = 0; q < 14; ++q) {
          float4 sr = *(const float4*)&sm.S[i][4*q];
          float4 s0 = *(const float4*)&sm.S[j0  ][4*q];
          float4 s1 = *(const float4*)&sm.S[j0+1][4*q];
          float4 s2 = *(const float4*)&sm.S[j0+2][4*q];
          float4 s3 = *(const float4*)&sm.S[j0+3][4*q];
          acc4(acc.x, sr, s0); acc4(acc.y, sr, s1); acc4(acc.z, sr, s2); acc4(acc.w, sr, s3);
        }
        sm.G0[i][j0] = acc.x; sm.G0[i][j0+1] = acc.y;
        sm.G0[i][j0+2] = acc.z; sm.G0[i][j0+3] = acc.w;
        ushort4 pk;
        pk.x = bf16r(acc.x); pk.y = bf16r(acc.y);
        pk.z = bf16r(acc.z); pk.w = bf16r(acc.w);
        *(ushort4*)&sm.ab.Abf[i][j0] = pk;     // bf16 copy for MFMA squarings
        mx = fmaxf(fmaxf(fabsf(acc.x), fabsf(acc.y)), fmaxf(fabsf(acc.z), fabsf(acc.w)));
      }
      if (wv < 14) {
        for (int off = 32; off; off >>= 1) mx = fmaxf(mx, __shfl_down(mx, off));
        if (lane == 0) atomicMax(&sm.gmax[0], __float_as_int(mx));
      } else {
        // zero Abf pads (clobbered by z this step): cols 56..63 of all 64 rows,
        // and rows 53..63 cols 0..55. (cols 64..79 are never read as fragments.)
        uint4 zz = make_uint4(0u, 0u, 0u, 0u);
        for (int l = tid - 896; l < 141; l += 128) {
          if (l < 64) {
            *(uint4*)&sm.ab.Abf[l][56] = zz;
          } else {
            int m = l - 64;                  // 0..76
            int r = 53 + m/7, cc = (m - 7*(m/7))*8;
            *(uint4*)&sm.ab.Abf[r][cc] = zz;
          }
        }
      }
    }
    __syncthreads();   // Abf = bf16(M_0), gmax[0] ready

    // ---------- 7 normalized squarings via MFMA (bf16 in / fp32 acc) ----------
    // M_{k+1} = (M_k @ M_k) / gmax[k]^2, stored bf16. Symmetric operand trick:
    // B[k][n] = M[k][n] = M[n][k], so both fragments are row-gathers of Abf.
    for (int k = 0; k < 7; ++k) {
      const unsigned short* rA = &sm.ab.Abf[16*tr + frow][0];
      const unsigned short* rB = &sm.ab.Abf[16*tc + frow][0];
      bf16x8 fa0 = *(const bf16x8*)((const char*)rA + fkb);
      bf16x8 fb0 = *(const bf16x8*)((const char*)rB + fkb);
      bf16x8 fa1 = *(const bf16x8*)((const char*)rA + 64 + fkb);   // k-step 1 (+32 bf16)
      bf16x8 fb1 = *(const bf16x8*)((const char*)rB + 64 + fkb);
      float s = 1.f/fmaxf(__int_as_float(sm.gmax[k]), 1e-20f);
      __syncthreads();                       // all reads of M_k complete
      f32x4 acc = {0.f, 0.f, 0.f, 0.f};
      acc = __builtin_amdgcn_mfma_f32_16x16x32_bf16(fa0, fb0, acc, 0, 0, 0);
      acc = __builtin_amdgcn_mfma_f32_16x16x32_bf16(fa1, fb1, acc, 0, 0, 0);
      float s2 = s*s;
      float c0v = acc[0]*s2, c1v = acc[1]*s2, c2v = acc[2]*s2, c3v = acc[3]*s2;
      float mx = fmaxf(fmaxf(fabsf(c0v), fabsf(c1v)), fmaxf(fabsf(c2v), fabsf(c3v)));
      for (int off = 32; off; off >>= 1) mx = fmaxf(mx, __shfl_down(mx, off));
      if (lane == 0) atomicMax(&sm.gmax[k+1], __float_as_int(mx));
      // C/D layout (verified): col = lane&15, row = (lane>>4)*4 + reg
      const int colb = 16*tc + (lane & 15);
      const int rowb = 16*tr + ((lane >> 4) << 2);
      sm.ab.Abf[rowb  ][colb] = bf16r(c0v);
      sm.ab.Abf[rowb+1][colb] = bf16r(c1v);
      sm.ab.Abf[rowb+2][colb] = bf16r(c2v);
      sm.ab.Abf[rowb+3][colb] = bf16r(c3v);
      __syncthreads();                       // M_{k+1} + gmax[k+1] ready
    }

    // ---------- Rayleigh tail: wave 0 only, in-wave LDS ordering (no barriers) ----------
    // pv from bf16 M_7 (starting vector only; ev comes from fp32 G0 below)
    if (wv == 0) {
      if (lane < 53) {
        float s = 0.f;
        for (int j = 0; j < 53; ++j) {
          float ph = 0.618034f*(float)(j + 1);
          float rj = 0.75f + 0.5f*(ph - floorf(ph));
          float av = __uint_as_float((unsigned)sm.ab.Abf[j][lane] << 16);
          s = fmaf(av, rj, s);
        }
        sm.pv[lane] = s;
      }
      __builtin_amdgcn_sched_barrier(0);
      if (lane < 53) {
        float s = 0.f;
        for (int j = 0; j < 53; ++j) s = fmaf(sm.G0[j][lane], sm.pv[j], s);
        sm.y1[lane] = s;
      }
      __builtin_amdgcn_sched_barrier(0);
      if (lane < 53) {
        float s = 0.f;
        for (int j = 0; j < 53; ++j) s = fmaf(sm.G0[j][lane], sm.y1[j], s);
        sm.y2[lane] = s;
      }
      __builtin_amdgcn_sched_barrier(0);
      float y3v = 0.f, y2v = 0.f;
      if (lane < 53) {
        float s = 0.f;
        for (int j = 0; j < 53; ++j) s = fmaf(sm.G0[j][lane], sm.y2[j], s);
        y3v = s; y2v = sm.y2[lane];
      }
      float num = y2v*y3v, den = y2v*y2v;
      for (int off = 32; off; off >>= 1) { num += __shfl_down(num, off); den += __shfl_down(den, off); }
      if (lane == 0) sm.sc_ev = sqrtf(num/fmaxf(den, 1e-30f));
    }
    __syncthreads();   // sc_ev visible

    // ---------- Phase 4a: attn = (S/ev)*sigmoid(|S/ev| + gate_b); write align ----------
    {
      float inv = 1.f/sm.sc_ev;
      const size_t abase = ((size_t)b*200 + (size_t)t)*2809;
      for (int idx = tid; idx < 2809; idx += NT) {
        int i = idx/53, j = idx - i*53;
        float s = sm.S[i][j]*inv;
        float a = s*fast_sigmoid(fabsf(s) + sm.gb[idx]);
        sm.S[i][j] = a;
        __builtin_nontemporal_store(a, &out_align[abase + idx]);
      }
    }
    __syncthreads();   // S rescaled

    // ---------- Phase 4b: h <- attn @ v (writes h cols 0..127; next step's input) ----------
    {
      const int f0 = (tid & 31)*4;
      const int io = tid >> 5;           // 0..31
      const int i1 = io + 32;
      const bool has1 = (i1 < 53);
      float4 acc0, acc1;
      acc0.x = acc0.y = acc0.z = acc0.w = 0.f;
      acc1 = acc0;
      for (int q = 0; q < 14; ++q) {
        float4 s0 = *(const float4*)&sm.S[io][4*q];
        float4 s1 = *(const float4*)&sm.S[has1 ? i1 : 0][4*q];
        int j = 4*q;
        float4 v0 = *(const float4*)&sm.v[j  ][f0];
        float4 v1 = *(const float4*)&sm.v[j+1][f0];
        float4 v2 = *(const float4*)&sm.v[j+2][f0];
        float4 v3 = *(const float4*)&sm.v[j+3][f0];
        FMA4(acc0, s0.x, v0); FMA4(acc0, s0.y, v1); FMA4(acc0, s0.z, v2); FMA4(acc0, s0.w, v3);
        FMA4(acc1, s1.x, v0); FMA4(acc1, s1.y, v1); FMA4(acc1, s1.z, v2); FMA4(acc1, s1.w, v3);
      }
      *(float4*)&sm.h[io][f0] = acc0;
      if (has1) *(float4*)&sm.h[i1][f0] = acc1;
      // next-iteration B1 synchronizes these writes
    }
  }
}

// ---------------- post-scan kernels (unchanged) ----------------

__global__ void mean_kernel(const float* __restrict__ align, float* __restrict__ m) {
  int idx = blockIdx.x*256 + threadIdx.x;
  if (idx >= 64*2809) return;
  int b = idx/2809, c = idx - b*2809;
  const float* p = align + (size_t)b*200*2809 + c;
  float s = 0.f;
  for (int t = 0; t < 200; ++t) s += p[(size_t)t*2809];
  m[idx] = s*(1.f/200.f);
}

__global__ void __launch_bounds__(256) xe_kernel(const float* __restrict__ align,
    const float* __restrict__ mai, const float* __restrict__ ge_w,
    const float* __restrict__ ge_b, float* __restrict__ xe) {
  __shared__ float sai[8][64];
  __shared__ float sw[64][140];
  const int tid = threadIdx.x;
  const int r0 = blockIdx.x*8;
  float4 acc0, acc1;
  acc0.x = acc0.y = acc0.z = acc0.w = 0.f;
  acc1 = acc0;
  const bool active = tid < 140;
  int rr0 = 0, cc0 = 0;
  if (active) { rr0 = (tid/35)*2; cc0 = (tid - 35*(tid/35))*4; }
  for (int k0 = 0; k0 < 2809; k0 += 64) {
    for (int l = tid; l < 512; l += 256) {
      int rr = l >> 6, kk = l & 63, k = k0 + kk;
      int r = r0 + rr;
      int bb = r/200;
      sai[rr][kk] = (k < 2809) ? align[(size_t)r*2809 + k]*mai[bb*2809 + k] : 0.f;
    }
    for (int l = tid; l < 64*140; l += 256) {
      int kk = l/140, cc = l - kk*140, k = k0 + kk;
      sw[kk][cc] = (k < 2809) ? ge_w[k*140 + cc] : 0.f;
    }
    __syncthreads();
    if (active) {
      for (int kk = 0; kk < 64; ++kk) {
        float a0 = sai[rr0][kk], a1 = sai[rr0+1][kk];
        float4 wv = *(const float4*)&sw[kk][cc0];
        FMA4(acc0, a0, wv); FMA4(acc1, a1, wv);
      }
    }
    __syncthreads();
  }
  if (active) {
    float4 gb = *(const float4*)&ge_b[cc0];
    acc0.x += gb.x; acc0.y += gb.y; acc0.z += gb.z; acc0.w += gb.w;
    acc1.x += gb.x; acc1.y += gb.y; acc1.z += gb.z; acc1.w += gb.w;
    *(float4*)&xe[(r0 + rr0)*140 + cc0]   = acc0;
    *(float4*)&xe[(r0 + rr0 + 1)*140 + cc0] = acc1;
  }
}

__global__ void bn_stats_kernel(const float* __restrict__ xe, float* __restrict__ mu,
                                float* __restrict__ var) {
  const int c = blockIdx.x, tid = threadIdx.x;
  double s = 0.0, sq = 0.0;
  for (int r = tid; r < 12800; r += 256) {
    double v = (double)xe[r*140 + c];
    s += v; sq += v*v;
  }
  for (int off = 32; off; off >>= 1) { s += __shfl_down(s, off); sq += __shfl_down(sq, off); }
  __shared__ double rs[4], rq[4];
  if ((tid & 63) == 0) { rs[tid >> 6] = s; rq[tid >> 6] = sq; }
  __syncthreads();
  if (tid == 0) {
    double S = rs[0]+rs[1]+rs[2]+rs[3], Q = rq[0]+rq[1]+rq[2]+rq[3];
    double m = S/12800.0;
    double v = Q/12800.0 - m*m;
    mu[c] = (float)m;
    var[c] = (float)fmax(v, 0.0);
  }
}

__global__ void __launch_bounds__(256) a_kernel(const float* __restrict__ xe,
    const float* __restrict__ mu, const float* __restrict__ var,
    const float* __restrict__ bn_g, const float* __restrict__ bn_b,
    const float* __restrict__ ga_w1, const float* __restrict__ ga_b1,
    const float* __restrict__ ga_w2, const float* __restrict__ ga_b2,
    float* __restrict__ a_out) {
  __shared__ float sxn[16][140];
  __shared__ float rsum[16];
  const int tid = threadIdx.x;
  const int r0 = blockIdx.x*16;
  for (int l = tid; l < 16*140; l += 256) {
    int rr = l/140, cc = l - rr*140;
    float v = xe[(r0 + rr)*140 + cc];
    float xn = (v - mu[cc])*rsqrtf(var[cc] + 1e-5f)*bn_g[cc] + bn_b[cc];
    sxn[rr][cc] = fmaxf(xn, 0.f);
  }
  if (tid < 16) rsum[tid] = 0.f;
  __syncthreads();
  float asum[16];
  #pragma unroll
  for (int r = 0; r < 16; ++r) asum[r] = 0.f;
  for (int j = tid; j < 1404; j += 256) {
    float acc[16];
    #pragma unroll
    for (int r = 0; r < 16; ++r) acc[r] = 0.f;
    for (int k = 0; k < 140; ++k) {
      float wv = ga_w1[k*1404 + j];
      #pragma unroll
      for (int r = 0; r < 16; ++r) acc[r] += sxn[r][k]*wv;
    }
    float b1 = ga_b1[j], w2 = ga_w2[j];
    #pragma unroll
    for (int r = 0; r < 16; ++r) asum[r] += fmaxf(acc[r] + b1, 0.f)*w2;
  }
  #pragma unroll
  for (int r = 0; r < 16; ++r) atomicAdd(&rsum[r], asum[r]);
  __syncthreads();
  if (tid < 16) a_out[r0 + tid] = rsum[tid] + ga_b2[0];
}

__global__ void softmax_kernel(const float* __restrict__ a, float* __restrict__ w) {
  const int b = blockIdx.x, tid = threadIdx.x;  // 64 threads
  float mx = -1e30f;
  for (int t = tid; t < 200; t += 64) mx = fmaxf(mx, a[b*200 + t]);
  for (int off = 32; off; off >>= 1) mx = fmaxf(mx, __shfl_down(mx, off));
  mx = __shfl(mx, 0);
  float s = 0.f;
  for (int t = tid; t < 200; t += 64) { float e = __expf(a[b*200 + t] - mx); w[b*200 + t] = e; s += e; }
  for (int off = 32; off; off >>= 1) s += __shfl_down(s, off);
  s = __shfl(s, 0);
  float inv = 1.f/s;
  for (int t = tid; t < 200; t += 64) w[b*200 + t] *= inv;
}

__global__ void dnc_kernel(const float* __restrict__ align, const float* __restrict__ w,
                           float* __restrict__ dnc) {
  int idx = blockIdx.x*256 + threadIdx.x;
  if (idx >= 64*2809) return;
  int b = idx/2809, c = idx - b*2809;
  const float* p = align + (size_t)b*200*2809 + c;
  const float* pw = w + b*200;
  float s = 0.f;
  for (int t = 0; t < 200; ++t) s += p[(size_t)t*2809]*pw[t];
  dnc[idx] = s;
}

__global__ void fc_relu_kernel(const float* __restrict__ in, const float* __restrict__ wgt,
    const float* __restrict__ bias, float* __restrict__ out, int rows, int K, int N) {
  int idx = blockIdx.x*256 + threadIdx.x;
  if (idx >= rows*N) return;
  int r = idx/N, j = idx - r*N;
  const float* pi = in + (size_t)r*K;
  float s = 0.f;
  for (int k = 0; k < K; ++k) s += pi[k]*wgt[k*N + j];
  out[idx] = fmaxf(s + bias[j], 0.f);
}

__global__ void fc_kernel(const float* __restrict__ in, const float* __restrict__ wgt,
    const float* __restrict__ bias, float* __restrict__ out, int rows, int K, int N) {
  int idx = blockIdx.x*256 + threadIdx.x;
  if (idx >= rows*N) return;
  int r = idx/N, j = idx - r*N;
  const float* pi = in + (size_t)r*K;
  float s = 0.f;
  for (int k = 0; k < K; ++k) s += pi[k]*wgt[k*N + j];
  out[idx] = s + bias[j];
}

extern "C" void kernel_launch(void* const* d_in, const int* in_sizes, int n_in,
                              void* d_out, int out_size, void* d_ws, size_t ws_size,
                              hipStream_t stream) {
  (void)in_sizes; (void)n_in; (void)out_size; (void)ws_size;
  const float* x      = (const float*)d_in[0];
  const float* emb_w  = (const float*)d_in[1];
  const float* emb_b  = (const float*)d_in[2];
  const float* w_ih   = (const float*)d_in[3];
  const float* w_hh   = (const float*)d_in[4];
  const float* b_ih   = (const float*)d_in[5];
  const float* b_hh   = (const float*)d_in[6];
  const float* q_w    = (const float*)d_in[7];
  const float* q_b    = (const float*)d_in[8];
  const float* k_w    = (const float*)d_in[9];
  const float* k_b    = (const float*)d_in[10];
  const float* v_w    = (const float*)d_in[11];
  const float* v_b    = (const float*)d_in[12];
  const float* gate_b = (const float*)d_in[13];
  const float* ge_w   = (const float*)d_in[14];
  const float* ge_b   = (const float*)d_in[15];
  const float* bn_g   = (const float*)d_in[16];
  const float* bn_b   = (const float*)d_in[17];
  const float* ga_w1  = (const float*)d_in[18];
  const float* ga_b1  = (const float*)d_in[19];
  const float* ga_w2  = (const float*)d_in[20];
  const float* ga_b2  = (const float*)d_in[21];
  const float* c_w1   = (const float*)d_in[22];
  const float* c_b1   = (const float*)d_in[23];
  const float* c_w2   = (const float*)d_in[24];
  const float* c_b2   = (const float*)d_in[25];
  const float* c_w3   = (const float*)d_in[26];
  const float* c_b3   = (const float*)d_in[27];

  float* out = (float*)d_out;
  float* out_logits = out;                    // 128
  float* out_dnc    = out + 128;              // 64*2809
  float* out_align  = out + 128 + 64*2809;    // 64*200*2809

  float* ws    = (float*)d_ws;
  float* w_Wp1 = ws;                          // 50688
  float* w_Wp2 = w_Wp1 + 50688;               // 33924
  float* w_m   = w_Wp2 + 33924;               // 179776
  float* w_xe  = w_m + 179776;                // 1792000
  float* w_mu  = w_xe + 1792000;              // 140
  float* w_var = w_mu + 140;                  // 140
  float* w_a   = w_var + 140;                 // 12800
  float* w_w   = w_a + 12800;                 // 12800
  float* w_h1  = w_w + 12800;                 // 89856
  float* w_h2  = w_h1 + 89856;                // 44928

  hipLaunchKernelGGL(prep_wp1, dim3((50688 + 255)/256), dim3(256), 0, stream, w_hh, b_hh, w_Wp1);
  hipLaunchKernelGGL(prep_wp2, dim3((33924 + 255)/256), dim3(256), 0, stream,
                     q_w, q_b, k_w, k_b, v_w, v_b, w_Wp2);

  const size_t shmem = sizeof(SmemScan);
  (void)hipFuncSetAttribute(reinterpret_cast<const void*>(scan_kernel),
                            hipFuncAttributeMaxDynamicSharedMemorySize, (int)shmem);

  hipLaunchKernelGGL(scan_kernel, dim3(64), dim3(1024), shmem, stream,
                     x, emb_w, emb_b, w_ih, b_ih, w_Wp1, w_Wp2, gate_b, out_align);

  hipLaunchKernelGGL(mean_kernel, dim3(703), dim3(256), 0, stream, out_align, w_m);
  hipLaunchKernelGGL(xe_kernel, dim3(1600), dim3(256), 0, stream, out_align, w_m, ge_w, ge_b, w_xe);
  hipLaunchKernelGGL(bn_stats_kernel, dim3(140), dim3(256), 0, stream, w_xe, w_mu, w_var);
  hipLaunchKernelGGL(a_kernel, dim3(800), dim3(256), 0, stream,
                     w_xe, w_mu, w_var, bn_g, bn_b, ga_w1, ga_b1, ga_w2, ga_b2, w_a);
  hipLaunchKernelGGL(softmax_kernel, dim3(64), dim3(64), 0, stream, w_a, w_w);
  hipLaunchKernelGGL(dnc_kernel, dim3(703), dim3(256), 0, stream, out_align, w_w, out_dnc);
  hipLaunchKernelGGL(fc_relu_kernel, dim3(351), dim3(256), 0, stream, out_dnc, c_w1, c_b1, w_h1, 64, 2809, 1404);
  hipLaunchKernelGGL(fc_relu_kernel, dim3(176), dim3(256), 0, stream, w_h1, c_w2, c_b2, w_h2, 64, 1404, 702);
  hipLaunchKernelGGL(fc_kernel, dim3(1), dim3(128), 0, stream, w_h2, c_w3, c_b3, out_logits, 64, 702, 2);
}